// Round 10
// baseline (635.364 us; speedup 1.0000x reference)
//
#include <hip/hip_runtime.h>

#define NN 100000
#define NE 1600000
#define NEO 400000
#define HID 64
#define NL 6
#define BN_EPS 1e-5f

#define SPMM_BLOCKS 6250        // 16 rows/block -> exactly one pass, max TLP
#define SCAN_BS 512
#define SCAN_NB 196   // ceil(100000/512)
#define GRP_ROWS 12500          // NN/8 rows per XCD group (build only)
#define BUILD_BPG 784           // blocks per group for build

// ---- d_ws layout (float offsets): 83.2MB ----
#define OFF_ECOL 0                        // NE ints
#define OFF_XE   NE                       // NN*64 f
#define OFF_AGG  (OFF_XE + NN * HID)      // NN*64 f
#define OFF_HWB  (OFF_AGG + NN * HID)     // NN*64 bf16 = NN*32 f
#define OFF_XEB  (OFF_HWB + NN * 32)      // NN*64 bf16 (final residual for k_out)

// ---- d_out head used as scratch (dead before k_out overwrites) ----
#define OD_DINV   0                      // NN f
#define OD_ROWPTR 100000                 // NN+1 ints (rounded 100352)
#define OD_CC     200352                 // NN ints (counts, then cursors)
#define OD_BSUM   300352                 // 256 ints
#define OD_SS     300608                 // 128 f (scale/shift)
#define OD_SUMS   300736                 // 16*128 doubles

typedef __attribute__((ext_vector_type(8))) short bf16x8;
typedef __attribute__((ext_vector_type(4))) float f32x4;

static __device__ __forceinline__ unsigned short f2bf(float f) {
    unsigned u = __float_as_uint(f);
    unsigned r = (u + 0x7FFF + ((u >> 16) & 1)) >> 16;  // RNE
    return (unsigned short)r;
}
static __device__ __forceinline__ float bflo(unsigned u) {
    return __uint_as_float(u << 16);
}
static __device__ __forceinline__ float bfhi(unsigned u) {
    return __uint_as_float(u & 0xFFFF0000u);
}

// single-pass histogram (R10: reverted R5 partitioning — 1x dst read, atomics are cheap;
// the XCD partition only pays off for k_build's payload writes)
__global__ void k_hist(const int* __restrict__ dst, int* __restrict__ cnt) {
    int e = blockIdx.x * blockDim.x + threadIdx.x;
    if (e < NE) atomicAdd(&cnt[dst[e]], 1);
}

__global__ void k_scanA(const int* __restrict__ cnt, int* __restrict__ rowptr,
                        int* __restrict__ bsum, float* __restrict__ dinv) {
    __shared__ int sh[SCAN_BS];
    int t = threadIdx.x;
    int i = blockIdx.x * SCAN_BS + t;
    int v = (i < NN) ? cnt[i] : 0;
    sh[t] = v;
    __syncthreads();
    for (int off = 1; off < SCAN_BS; off <<= 1) {
        int a = (t >= off) ? sh[t - off] : 0;
        __syncthreads();
        sh[t] += a;
        __syncthreads();
    }
    if (i < NN) {
        rowptr[i] = sh[t] - v;
        dinv[i] = rsqrtf((float)(v + 1));   // deg = in-deg + self-loop
    }
    if (t == SCAN_BS - 1) bsum[blockIdx.x] = sh[t];
}

__global__ void k_scanB(int* __restrict__ bsum) {
    __shared__ int sh[256];
    int t = threadIdx.x;
    int v = (t < SCAN_NB) ? bsum[t] : 0;
    sh[t] = v;
    __syncthreads();
    for (int off = 1; off < 256; off <<= 1) {
        int a = (t >= off) ? sh[t - off] : 0;
        __syncthreads();
        sh[t] += a;
        __syncthreads();
    }
    if (t < SCAN_NB) bsum[t] = (t == 0) ? 0 : sh[t - 1];
}

__global__ void k_scanC(int* __restrict__ rowptr, const int* __restrict__ bsum,
                        int* __restrict__ cursor) {
    int i = blockIdx.x * SCAN_BS + threadIdx.x;
    if (i < NN) {
        int rp = rowptr[i] + bsum[blockIdx.x];
        rowptr[i] = rp;
        cursor[i] = rp;
    }
    if (i == 0) rowptr[NN] = NE;
}

// XCD-partitioned CSR scatter (validated R4->R5 win)
__global__ void k_build(const int* __restrict__ src, const int* __restrict__ dst,
                        int* __restrict__ cursor, int* __restrict__ ecol) {
    int g = blockIdx.x & 7;
    int b = blockIdx.x >> 3;
    int lo = g * GRP_ROWS, hi = lo + GRP_ROWS;
    for (int e = b * blockDim.x + threadIdx.x; e < NE; e += BUILD_BPG * blockDim.x) {
        int d = dst[e];
        if (d >= lo && d < hi) {
            int pos = atomicAdd(&cursor[d], 1);
            ecol[pos] = src[e];
        }
    }
}

// xe = x[NN,16] @ W[16,64] + b
__global__ void k_embed(const float* __restrict__ x, const float* __restrict__ W,
                        const float* __restrict__ b, float* __restrict__ xe) {
    __shared__ float Ws[16 * 64];
    __shared__ float bs[64];
    int t = threadIdx.x;
    for (int i = t; i < 16 * 64; i += 256) Ws[i] = W[i];
    if (t < 64) bs[t] = b[t];
    __syncthreads();
    int c = t & 63, r = t >> 6;
    int n0 = blockIdx.x * 64;
    for (int n = n0 + r; n < n0 + 64 && n < NN; n += 4) {
        const float* xr = x + n * 16;
        float acc = bs[c];
#pragma unroll
        for (int k = 0; k < 16; k++) acc = fmaf(xr[k], Ws[k * 64 + c], acc);
        xe[n * 64 + c] = acc;
    }
}

// fused: xe += relu(agg*sc+sh) (prev BN, if apply); hwb = bf16(dinv*(xe@W))  [MFMA]
__global__ void k_hw(const float* __restrict__ xeIn, float* __restrict__ xe,
                     const float* __restrict__ W, const float* __restrict__ dinv,
                     const float* __restrict__ agg, const float* __restrict__ ss,
                     unsigned short* __restrict__ hwb, double* __restrict__ sums,
                     int apply) {
    __shared__ unsigned short Wt[64 * 72];   // Wt[c][k], pitch 72
    __shared__ unsigned short Xb[64 * 72];   // Xb[n][k]
    __shared__ float sss[128];
    int t = threadIdx.x;
    int n0 = blockIdx.x * 64;
    if (blockIdx.x == 0) {
        for (int i = t; i < 16 * 128; i += 256) sums[i] = 0.0;
    }
    if (t < 128) sss[t] = apply ? ss[t] : 0.f;

    {   // stage Wt (transpose, bf16)
        int c = t & 63, r = t >> 6;
#pragma unroll
        for (int jj = 0; jj < 4; jj++) {
            float w0 = W[(r * 16 + jj * 4 + 0) * 64 + c];
            float w1 = W[(r * 16 + jj * 4 + 1) * 64 + c];
            float w2 = W[(r * 16 + jj * 4 + 2) * 64 + c];
            float w3 = W[(r * 16 + jj * 4 + 3) * 64 + c];
            uint2 pk;
            pk.x = ((unsigned)f2bf(w1) << 16) | f2bf(w0);
            pk.y = ((unsigned)f2bf(w3) << 16) | f2bf(w2);
            *(uint2*)&Wt[c * 72 + r * 16 + jj * 4] = pk;
        }
    }
    __syncthreads();

    {   // stage Xb (+apply fusion)
        int n = t >> 2, kq = t & 3;
        int node = n0 + n;
        float4 xv[4];
        if (node < NN) {
            const float4* xr = (const float4*)(xeIn + (size_t)node * 64 + kq * 16);
#pragma unroll
            for (int i = 0; i < 4; i++) xv[i] = xr[i];
            if (apply) {
                const float4* ar = (const float4*)(agg + (size_t)node * 64 + kq * 16);
                float4* xw = (float4*)(xe + (size_t)node * 64 + kq * 16);
#pragma unroll
                for (int i = 0; i < 4; i++) {
                    float4 av = ar[i];
                    int c = kq * 16 + i * 4;
                    xv[i].x += fmaxf(fmaf(av.x, sss[c + 0], sss[64 + c + 0]), 0.f);
                    xv[i].y += fmaxf(fmaf(av.y, sss[c + 1], sss[64 + c + 1]), 0.f);
                    xv[i].z += fmaxf(fmaf(av.z, sss[c + 2], sss[64 + c + 2]), 0.f);
                    xv[i].w += fmaxf(fmaf(av.w, sss[c + 3], sss[64 + c + 3]), 0.f);
                    xw[i] = xv[i];
                }
            }
        } else {
#pragma unroll
            for (int i = 0; i < 4; i++) xv[i] = make_float4(0.f, 0.f, 0.f, 0.f);
        }
#pragma unroll
        for (int i = 0; i < 4; i++) {
            uint2 pk;
            pk.x = ((unsigned)f2bf(xv[i].y) << 16) | f2bf(xv[i].x);
            pk.y = ((unsigned)f2bf(xv[i].w) << 16) | f2bf(xv[i].z);
            *(uint2*)&Xb[n * 72 + kq * 16 + i * 4] = pk;
        }
    }
    __syncthreads();

    int lane = t & 63, w = t >> 6;
    int m = lane & 15, quad = lane >> 4;
    f32x4 acc[4];
#pragma unroll
    for (int tc = 0; tc < 4; tc++) acc[tc] = (f32x4){0.f, 0.f, 0.f, 0.f};
#pragma unroll
    for (int s = 0; s < 2; s++) {
        bf16x8 bfr = *(const bf16x8*)&Xb[(w * 16 + m) * 72 + s * 32 + quad * 8];
#pragma unroll
        for (int tc = 0; tc < 4; tc++) {
            bf16x8 afr = *(const bf16x8*)&Wt[(tc * 16 + m) * 72 + s * 32 + quad * 8];
            acc[tc] = __builtin_amdgcn_mfma_f32_16x16x32_bf16(afr, bfr, acc[tc], 0, 0, 0);
        }
    }
    int node = n0 + w * 16 + m;
    if (node < NN) {
        float di = dinv[node];
#pragma unroll
        for (int tc = 0; tc < 4; tc++) {
            int c0 = tc * 16 + quad * 4;
            uint2 pk;
            pk.x = ((unsigned)f2bf(acc[tc][1] * di) << 16) | f2bf(acc[tc][0] * di);
            pk.y = ((unsigned)f2bf(acc[tc][3] * di) << 16) | f2bf(acc[tc][2] * di);
            *(uint2*)(hwb + (size_t)node * 64 + c0) = pk;
        }
    }
}

// agg[d] = dinv[d]*(hwb[d] + sum_{s in N(d)} hwb[s]); fused BN stats.
// Wave = 4 rows x 16 lanes (2 sub-groups of 8); lane q holds ch 8q..8q+7 (uint4).
__global__ void k_spmm(const int* __restrict__ rowptr, const int* __restrict__ ecol,
                       const unsigned short* __restrict__ hwb, const float* __restrict__ dinv,
                       float* __restrict__ agg, double* __restrict__ sums) {
    int t = threadIdx.x;
    int w = t >> 6, l = t & 63;
    int r = l >> 4;          // row slot 0..3
    int sub = (l >> 3) & 1;  // edge sub-group
    int q = l & 7;           // channel quad
    const uint4* hw4 = (const uint4*)hwb;
    float ls[8], lq[8];
#pragma unroll
    for (int j = 0; j < 8; j++) { ls[j] = 0.f; lq[j] = 0.f; }
    for (int row0 = blockIdx.x * 16 + w * 4; row0 < NN; row0 += SPMM_BLOCKS * 16) {
        int row = row0 + r;
        bool valid = row < NN;
        int p0 = 0, p1 = 0;
        float a[8];
#pragma unroll
        for (int j = 0; j < 8; j++) a[j] = 0.f;
        if (valid) {
            p0 = rowptr[row];
            p1 = rowptr[row + 1];
            if (sub == 0) {   // count self-term once
                uint4 sv = hw4[(size_t)row * 8 + q];
                a[0] = bflo(sv.x); a[1] = bfhi(sv.x); a[2] = bflo(sv.y); a[3] = bfhi(sv.y);
                a[4] = bflo(sv.z); a[5] = bfhi(sv.z); a[6] = bflo(sv.w); a[7] = bfhi(sv.w);
            }
        }
        int p = p0 + sub;
        for (; p + 2 < p1; p += 4) {      // unroll 2
            int s0 = ecol[p], s1 = ecol[p + 2];
            uint4 u0 = hw4[(size_t)s0 * 8 + q];
            uint4 u1 = hw4[(size_t)s1 * 8 + q];
            a[0] += bflo(u0.x); a[1] += bfhi(u0.x); a[2] += bflo(u0.y); a[3] += bfhi(u0.y);
            a[4] += bflo(u0.z); a[5] += bfhi(u0.z); a[6] += bflo(u0.w); a[7] += bfhi(u0.w);
            a[0] += bflo(u1.x); a[1] += bfhi(u1.x); a[2] += bflo(u1.y); a[3] += bfhi(u1.y);
            a[4] += bflo(u1.z); a[5] += bfhi(u1.z); a[6] += bflo(u1.w); a[7] += bfhi(u1.w);
        }
        if (p < p1) {
            int s0 = ecol[p];
            uint4 u0 = hw4[(size_t)s0 * 8 + q];
            a[0] += bflo(u0.x); a[1] += bfhi(u0.x); a[2] += bflo(u0.y); a[3] += bfhi(u0.y);
            a[4] += bflo(u0.z); a[5] += bfhi(u0.z); a[6] += bflo(u0.w); a[7] += bfhi(u0.w);
        }
#pragma unroll
        for (int j = 0; j < 8; j++) a[j] += __shfl_xor(a[j], 8, 64);  // merge sub-groups
        if (valid && sub == 0) {
            float di = dinv[row];
            float v[8];
#pragma unroll
            for (int j = 0; j < 8; j++) v[j] = a[j] * di;
            float4 o0 = make_float4(v[0], v[1], v[2], v[3]);
            float4 o1 = make_float4(v[4], v[5], v[6], v[7]);
            *(float4*)(agg + (size_t)row * 64 + 8 * q) = o0;
            *(float4*)(agg + (size_t)row * 64 + 8 * q + 4) = o1;
#pragma unroll
            for (int j = 0; j < 8; j++) {
                ls[j] += v[j];
                lq[j] = fmaf(v[j], v[j], lq[j]);
            }
        }
    }
#pragma unroll
    for (int j = 0; j < 8; j++) {
        ls[j] += __shfl_xor(ls[j], 16, 64); ls[j] += __shfl_xor(ls[j], 32, 64);
        lq[j] += __shfl_xor(lq[j], 16, 64); lq[j] += __shfl_xor(lq[j], 32, 64);
    }
    __shared__ float Ss[4][64], Sq[4][64];
    if (l < 8) {   // r==0, sub==0, q=l
#pragma unroll
        for (int j = 0; j < 8; j++) {
            Ss[w][8 * l + j] = ls[j];
            Sq[w][8 * l + j] = lq[j];
        }
    }
    __syncthreads();
    if (t < 64) {
        float a = Ss[0][t] + Ss[1][t] + Ss[2][t] + Ss[3][t];
        float b = Sq[0][t] + Sq[1][t] + Sq[2][t] + Sq[3][t];
        double* sh = sums + (blockIdx.x & 15) * 128;
        atomicAdd(&sh[t], (double)a);
        atomicAdd(&sh[64 + t], (double)b);
    }
}

__global__ void k_finalize(const double* __restrict__ sums, const float* __restrict__ gamma,
                           const float* __restrict__ beta, float* __restrict__ ss) {
    int c = threadIdx.x;  // 64 threads
    double s = 0.0, q = 0.0;
#pragma unroll
    for (int k = 0; k < 16; k++) { s += sums[k * 128 + c]; q += sums[k * 128 + 64 + c]; }
    double mean = s / (double)NN;
    double var = q / (double)NN - mean * mean;
    float sc = gamma[c] * rsqrtf((float)var + BN_EPS);
    ss[c] = sc;
    ss[64 + c] = beta[c] - (float)mean * sc;
}

// final layer: xeb = bf16(xe + relu(agg*scale + shift))  (k_out reads bf16 rows)
__global__ void k_apply(const float* __restrict__ agg, const float* __restrict__ ss,
                        const float* __restrict__ xe, unsigned* __restrict__ xeb) {
    int i = blockIdx.x * blockDim.x + threadIdx.x;   // over NN*32 pairs
    if (i < NN * 32) {
        int i2 = i * 2;
        int c = i2 & 63;
        float2 av = *(const float2*)(agg + i2);
        float2 xv = *(const float2*)(xe + i2);
        float v0 = xv.x + fmaxf(fmaf(av.x, ss[c], ss[64 + c]), 0.f);
        float v1 = xv.y + fmaxf(fmaf(av.y, ss[c + 1], ss[64 + c + 1]), 0.f);
        xeb[i] = ((unsigned)f2bf(v1) << 16) | f2bf(v0);
    }
}

// out[e] = [xeb[s]; xeb[d]] @ fc_W + fc_b   (bf16 rows: 128B/row gather, half of fp32)
__global__ void k_out(const int* __restrict__ esrc, const int* __restrict__ edst,
                      const unsigned short* __restrict__ xeb, const float* __restrict__ fcW,
                      const float* __restrict__ fcb, float* __restrict__ out) {
    __shared__ float Ws[256];
    __shared__ float bs[2];
    int t = threadIdx.x;
    for (int i = t; i < 256; i += 256) Ws[i] = fcW[i];
    if (t < 2) bs[t] = fcb[t];
    __syncthreads();
    int e = blockIdx.x * blockDim.x + t;
    if (e < NEO) {
        int s = esrc[e], d = edst[e];
        const uint4* rs = (const uint4*)(xeb + (size_t)s * 64);
        const uint4* rd = (const uint4*)(xeb + (size_t)d * 64);
        float a0 = bs[0], a1 = bs[1];
#pragma unroll
        for (int i = 0; i < 8; i++) {
            uint4 v = rs[i];
            int c = i * 8;
            a0 += bflo(v.x) * Ws[(c + 0) * 2] + bfhi(v.x) * Ws[(c + 1) * 2] +
                  bflo(v.y) * Ws[(c + 2) * 2] + bfhi(v.y) * Ws[(c + 3) * 2] +
                  bflo(v.z) * Ws[(c + 4) * 2] + bfhi(v.z) * Ws[(c + 5) * 2] +
                  bflo(v.w) * Ws[(c + 6) * 2] + bfhi(v.w) * Ws[(c + 7) * 2];
            a1 += bflo(v.x) * Ws[(c + 0) * 2 + 1] + bfhi(v.x) * Ws[(c + 1) * 2 + 1] +
                  bflo(v.y) * Ws[(c + 2) * 2 + 1] + bfhi(v.y) * Ws[(c + 3) * 2 + 1] +
                  bflo(v.z) * Ws[(c + 4) * 2 + 1] + bfhi(v.z) * Ws[(c + 5) * 2 + 1] +
                  bflo(v.w) * Ws[(c + 6) * 2 + 1] + bfhi(v.w) * Ws[(c + 7) * 2 + 1];
        }
#pragma unroll
        for (int i = 0; i < 8; i++) {
            uint4 v = rd[i];
            int c = 64 + i * 8;
            a0 += bflo(v.x) * Ws[(c + 0) * 2] + bfhi(v.x) * Ws[(c + 1) * 2] +
                  bflo(v.y) * Ws[(c + 2) * 2] + bfhi(v.y) * Ws[(c + 3) * 2] +
                  bflo(v.z) * Ws[(c + 4) * 2] + bfhi(v.z) * Ws[(c + 5) * 2] +
                  bflo(v.w) * Ws[(c + 6) * 2] + bfhi(v.w) * Ws[(c + 7) * 2];
            a1 += bflo(v.x) * Ws[(c + 0) * 2 + 1] + bfhi(v.x) * Ws[(c + 1) * 2 + 1] +
                  bflo(v.y) * Ws[(c + 2) * 2 + 1] + bfhi(v.y) * Ws[(c + 3) * 2 + 1] +
                  bflo(v.z) * Ws[(c + 4) * 2 + 1] + bfhi(v.z) * Ws[(c + 5) * 2 + 1] +
                  bflo(v.w) * Ws[(c + 6) * 2 + 1] + bfhi(v.w) * Ws[(c + 7) * 2 + 1];
        }
        out[e * 2] = a0;
        out[e * 2 + 1] = a1;
    }
}

extern "C" void kernel_launch(void* const* d_in, const int* in_sizes, int n_in,
                              void* d_out, int out_size, void* d_ws, size_t ws_size,
                              hipStream_t stream) {
    const float* x      = (const float*)d_in[0];
    const int*   ei     = (const int*)d_in[1];
    const int*   eio    = (const int*)d_in[2];
    const float* W_emb  = (const float*)d_in[3];
    const float* b_emb  = (const float*)d_in[4];
    const float* conv_W = (const float*)d_in[5];
    // d_in[6] conv_b: cancels inside BN
    const float* bn_g   = (const float*)d_in[7];
    const float* bn_b   = (const float*)d_in[8];
    const float* fc_W   = (const float*)d_in[9];
    const float* fc_b   = (const float*)d_in[10];
    float* out = (float*)d_out;

    float* ws   = (float*)d_ws;
    int*   ecol = (int*)(ws + OFF_ECOL);
    float* xe   = ws + OFF_XE;
    float* agg  = ws + OFF_AGG;
    unsigned short* hwb = (unsigned short*)(ws + OFF_HWB);
    unsigned* xeb = (unsigned*)(ws + OFF_XEB);

    float* od     = (float*)d_out;
    float* dinv   = od + OD_DINV;
    int*   rowptr = (int*)(od + OD_ROWPTR);
    int*   cc     = (int*)(od + OD_CC);
    int*   bsum   = (int*)(od + OD_BSUM);
    float* ss     = od + OD_SS;
    double* sums  = (double*)(od + OD_SUMS);

    const int* src  = ei;
    const int* dst  = ei + NE;
    const int* esrc = eio;
    const int* edst = eio + NEO;

    // ---- one-time CSR build ----
    (void)hipMemsetAsync(cc, 0, NN * sizeof(int), stream);
    k_hist<<<(NE + 255) / 256, 256, 0, stream>>>(dst, cc);
    k_scanA<<<SCAN_NB, SCAN_BS, 0, stream>>>(cc, rowptr, bsum, dinv);
    k_scanB<<<1, 256, 0, stream>>>(bsum);
    k_scanC<<<SCAN_NB, SCAN_BS, 0, stream>>>(rowptr, bsum, cc);
    k_build<<<8 * BUILD_BPG, 256, 0, stream>>>(src, dst, cc, ecol);

    k_embed<<<(NN + 63) / 64, 256, 0, stream>>>(x, W_emb, b_emb, xe);

    for (int l = 0; l < NL; l++) {
        k_hw<<<(NN + 63) / 64, 256, 0, stream>>>(xe, xe, conv_W + l * 64 * 64, dinv,
                                                 agg, ss, hwb, sums, l > 0 ? 1 : 0);
        k_spmm<<<SPMM_BLOCKS, 256, 0, stream>>>(rowptr, ecol, hwb, dinv, agg, sums);
        k_finalize<<<1, 64, 0, stream>>>(sums, bn_g + l * 64, bn_b + l * 64, ss);
    }
    k_apply<<<(NN * 32 + 255) / 256, 256, 0, stream>>>(agg, ss, xe, xeb);

    k_out<<<(NEO + 255) / 256, 256, 0, stream>>>(esrc, edst, (const unsigned short*)xeb,
                                                 fc_W, fc_b, out);
}

// Round 14
// 626.864 us; speedup vs baseline: 1.0136x; 1.0136x over previous
//
#include <hip/hip_runtime.h>

#define NN 100000
#define NE 1600000
#define NEO 400000
#define HID 64
#define NL 6
#define BN_EPS 1e-5f

#define SPMM_BLOCKS 6250
#define SCAN_BS 512
#define SCAN_NB 196   // ceil(100000/512)
#define GRP_ROWS 12500          // NN/8 rows per XCD group (build only)
#define BUILD_BPG 784           // blocks per group for build

// ---- d_ws layout (float offsets): 83.2MB ----
#define OFF_ECOL 0                        // NE ints
#define OFF_XE   NE                       // NN*64 f
#define OFF_AGG  (OFF_XE + NN * HID)      // NN*64 f
#define OFF_HWB  (OFF_AGG + NN * HID)     // NN*64 bf16
#define OFF_XEB  (OFF_HWB + NN * 32)      // NN*64 bf16 (final residual for k_out)

// ---- d_out head used as scratch (dead before k_out overwrites) ----
#define OD_DINV   0                      // NN f
#define OD_ROWPTR 100352                 // NN+1 ints
#define OD_CC     200704                 // NN ints (counts, then cursors)
#define OD_BSUM   300704                 // 256 ints
#define OD_SS     300960                 // 128 f (scale/shift, final layer)
#define OD_SUMS   301088                 // 2 x 2048 doubles (ping-pong), 8B-aligned

typedef __attribute__((ext_vector_type(8))) short bf16x8;
typedef __attribute__((ext_vector_type(4))) float f32x4;

static __device__ __forceinline__ unsigned short f2bf(float f) {
    unsigned u = __float_as_uint(f);
    unsigned r = (u + 0x7FFF + ((u >> 16) & 1)) >> 16;  // RNE
    return (unsigned short)r;
}
static __device__ __forceinline__ float bflo(unsigned u) {
    return __uint_as_float(u << 16);
}
static __device__ __forceinline__ float bfhi(unsigned u) {
    return __uint_as_float(u & 0xFFFF0000u);
}

// single-pass histogram (proven R10)
__global__ void k_hist(const int* __restrict__ dst, int* __restrict__ cnt) {
    int e = blockIdx.x * blockDim.x + threadIdx.x;
    if (e < NE) atomicAdd(&cnt[dst[e]], 1);
}

__global__ void k_scanA(const int* __restrict__ cnt, int* __restrict__ rowptr,
                        int* __restrict__ bsum, float* __restrict__ dinv) {
    __shared__ int sh[SCAN_BS];
    int t = threadIdx.x;
    int i = blockIdx.x * SCAN_BS + t;
    int v = (i < NN) ? cnt[i] : 0;
    sh[t] = v;
    __syncthreads();
    for (int off = 1; off < SCAN_BS; off <<= 1) {
        int a = (t >= off) ? sh[t - off] : 0;
        __syncthreads();
        sh[t] += a;
        __syncthreads();
    }
    if (i < NN) {
        rowptr[i] = sh[t] - v;
        dinv[i] = rsqrtf((float)(v + 1));   // deg = in-deg + self-loop
    }
    if (t == SCAN_BS - 1) bsum[blockIdx.x] = sh[t];
}

__global__ void k_scanB(int* __restrict__ bsum) {
    __shared__ int sh[256];
    int t = threadIdx.x;
    int v = (t < SCAN_NB) ? bsum[t] : 0;
    sh[t] = v;
    __syncthreads();
    for (int off = 1; off < 256; off <<= 1) {
        int a = (t >= off) ? sh[t - off] : 0;
        __syncthreads();
        sh[t] += a;
        __syncthreads();
    }
    if (t < SCAN_NB) bsum[t] = (t == 0) ? 0 : sh[t - 1];
}

__global__ void k_scanC(int* __restrict__ rowptr, const int* __restrict__ bsum,
                        int* __restrict__ cursor) {
    int i = blockIdx.x * SCAN_BS + threadIdx.x;
    if (i < NN) {
        int rp = rowptr[i] + bsum[blockIdx.x];
        rowptr[i] = rp;
        cursor[i] = rp;
    }
    if (i == 0) rowptr[NN] = NE;
}

// XCD-partitioned CSR scatter (proven R5..R10)
__global__ void k_build(const int* __restrict__ src, const int* __restrict__ dst,
                        int* __restrict__ cursor, int* __restrict__ ecol) {
    int g = blockIdx.x & 7;
    int b = blockIdx.x >> 3;
    int lo = g * GRP_ROWS, hi = lo + GRP_ROWS;
    for (int e = b * blockDim.x + threadIdx.x; e < NE; e += BUILD_BPG * blockDim.x) {
        int d = dst[e];
        if (d >= lo && d < hi) {
            int pos = atomicAdd(&cursor[d], 1);
            ecol[pos] = src[e];
        }
    }
}

// xe = x[NN,16] @ W[16,64] + b
__global__ void k_embed(const float* __restrict__ x, const float* __restrict__ W,
                        const float* __restrict__ b, float* __restrict__ xe) {
    __shared__ float Ws[16 * 64];
    __shared__ float bs[64];
    int t = threadIdx.x;
    for (int i = t; i < 16 * 64; i += 256) Ws[i] = W[i];
    if (t < 64) bs[t] = b[t];
    __syncthreads();
    int c = t & 63, r = t >> 6;
    int n0 = blockIdx.x * 64;
    for (int n = n0 + r; n < n0 + 64 && n < NN; n += 4) {
        const float* xr = x + n * 16;
        float acc = bs[c];
#pragma unroll
        for (int k = 0; k < 16; k++) acc = fmaf(xr[k], Ws[k * 64 + c], acc);
        xe[n * 64 + c] = acc;
    }
}

// fused: BN-finalize (from sumsPrev) + xe += relu(...) + hwb = bf16(dinv*(xe@W)) [MFMA]
// block 0 zeroes sumsCur (ping-pong -> no read/zero race; consumers are 1 layer behind)
__global__ void k_hw(const float* __restrict__ xeIn, float* __restrict__ xe,
                     const float* __restrict__ W, const float* __restrict__ dinv,
                     const float* __restrict__ agg,
                     const float* __restrict__ gamma, const float* __restrict__ beta,
                     const double* __restrict__ sumsPrev, double* __restrict__ sumsCur,
                     unsigned short* __restrict__ hwb, int apply) {
    __shared__ unsigned short Wt[64 * 72];   // Wt[c][k], pitch 72
    __shared__ unsigned short Xb[64 * 72];   // Xb[n][k]
    __shared__ float sss[128];
    int t = threadIdx.x;
    int n0 = blockIdx.x * 64;
    if (blockIdx.x == 0) {
        for (int i = t; i < 2048; i += 256) sumsCur[i] = 0.0;
    }
    if (apply && t < 64) {   // in-block BN finalize (replaces k_finalize launch)
        double s = 0.0, q = 0.0;
#pragma unroll
        for (int k = 0; k < 16; k++) {
            s += sumsPrev[k * 128 + t];
            q += sumsPrev[k * 128 + 64 + t];
        }
        double mean = s / (double)NN;
        double var = q / (double)NN - mean * mean;
        float sc = gamma[t] * rsqrtf((float)var + BN_EPS);
        sss[t] = sc;
        sss[64 + t] = beta[t] - (float)mean * sc;
    }

    {   // stage Wt (transpose, bf16)
        int c = t & 63, r = t >> 6;
#pragma unroll
        for (int jj = 0; jj < 4; jj++) {
            float w0 = W[(r * 16 + jj * 4 + 0) * 64 + c];
            float w1 = W[(r * 16 + jj * 4 + 1) * 64 + c];
            float w2 = W[(r * 16 + jj * 4 + 2) * 64 + c];
            float w3 = W[(r * 16 + jj * 4 + 3) * 64 + c];
            uint2 pk;
            pk.x = ((unsigned)f2bf(w1) << 16) | f2bf(w0);
            pk.y = ((unsigned)f2bf(w3) << 16) | f2bf(w2);
            *(uint2*)&Wt[c * 72 + r * 16 + jj * 4] = pk;
        }
    }
    __syncthreads();   // Wt + sss ready

    {   // stage Xb (+apply fusion)
        int n = t >> 2, kq = t & 3;
        int node = n0 + n;
        float4 xv[4];
        if (node < NN) {
            const float4* xr = (const float4*)(xeIn + (size_t)node * 64 + kq * 16);
#pragma unroll
            for (int i = 0; i < 4; i++) xv[i] = xr[i];
            if (apply) {
                const float4* ar = (const float4*)(agg + (size_t)node * 64 + kq * 16);
                float4* xw = (float4*)(xe + (size_t)node * 64 + kq * 16);
#pragma unroll
                for (int i = 0; i < 4; i++) {
                    float4 av = ar[i];
                    int c = kq * 16 + i * 4;
                    xv[i].x += fmaxf(fmaf(av.x, sss[c + 0], sss[64 + c + 0]), 0.f);
                    xv[i].y += fmaxf(fmaf(av.y, sss[c + 1], sss[64 + c + 1]), 0.f);
                    xv[i].z += fmaxf(fmaf(av.z, sss[c + 2], sss[64 + c + 2]), 0.f);
                    xv[i].w += fmaxf(fmaf(av.w, sss[c + 3], sss[64 + c + 3]), 0.f);
                    xw[i] = xv[i];
                }
            }
        } else {
#pragma unroll
            for (int i = 0; i < 4; i++) xv[i] = make_float4(0.f, 0.f, 0.f, 0.f);
        }
#pragma unroll
        for (int i = 0; i < 4; i++) {
            uint2 pk;
            pk.x = ((unsigned)f2bf(xv[i].y) << 16) | f2bf(xv[i].x);
            pk.y = ((unsigned)f2bf(xv[i].w) << 16) | f2bf(xv[i].z);
            *(uint2*)&Xb[n * 72 + kq * 16 + i * 4] = pk;
        }
    }
    __syncthreads();

    int lane = t & 63, w = t >> 6;
    int m = lane & 15, quad = lane >> 4;
    f32x4 acc[4];
#pragma unroll
    for (int tc = 0; tc < 4; tc++) acc[tc] = (f32x4){0.f, 0.f, 0.f, 0.f};
#pragma unroll
    for (int s = 0; s < 2; s++) {
        bf16x8 bfr = *(const bf16x8*)&Xb[(w * 16 + m) * 72 + s * 32 + quad * 8];
#pragma unroll
        for (int tc = 0; tc < 4; tc++) {
            bf16x8 afr = *(const bf16x8*)&Wt[(tc * 16 + m) * 72 + s * 32 + quad * 8];
            acc[tc] = __builtin_amdgcn_mfma_f32_16x16x32_bf16(afr, bfr, acc[tc], 0, 0, 0);
        }
    }
    int node = n0 + w * 16 + m;
    if (node < NN) {
        float di = dinv[node];
#pragma unroll
        for (int tc = 0; tc < 4; tc++) {
            int c0 = tc * 16 + quad * 4;
            uint2 pk;
            pk.x = ((unsigned)f2bf(acc[tc][1] * di) << 16) | f2bf(acc[tc][0] * di);
            pk.y = ((unsigned)f2bf(acc[tc][3] * di) << 16) | f2bf(acc[tc][2] * di);
            *(uint2*)(hwb + (size_t)node * 64 + c0) = pk;
        }
    }
}

// agg[d] = dinv[d]*(hwb[d] + sum_{s in N(d)} hwb[s]); fused BN stats.
// Wave = 4 rows x 16 lanes (2 sub-groups of 8); lane q holds ch 8q..8q+7 (uint4).
__global__ void k_spmm(const int* __restrict__ rowptr, const int* __restrict__ ecol,
                       const unsigned short* __restrict__ hwb, const float* __restrict__ dinv,
                       float* __restrict__ agg, double* __restrict__ sums) {
    int t = threadIdx.x;
    int w = t >> 6, l = t & 63;
    int r = l >> 4;          // row slot 0..3
    int sub = (l >> 3) & 1;  // edge sub-group
    int q = l & 7;           // channel quad
    const uint4* hw4 = (const uint4*)hwb;
    float ls[8], lq[8];
#pragma unroll
    for (int j = 0; j < 8; j++) { ls[j] = 0.f; lq[j] = 0.f; }
    for (int row0 = blockIdx.x * 16 + w * 4; row0 < NN; row0 += SPMM_BLOCKS * 16) {
        int row = row0 + r;
        bool valid = row < NN;
        int p0 = 0, p1 = 0;
        float a[8];
#pragma unroll
        for (int j = 0; j < 8; j++) a[j] = 0.f;
        if (valid) {
            p0 = rowptr[row];
            p1 = rowptr[row + 1];
            if (sub == 0) {
                uint4 sv = hw4[(size_t)row * 8 + q];
                a[0] = bflo(sv.x); a[1] = bfhi(sv.x); a[2] = bflo(sv.y); a[3] = bfhi(sv.y);
                a[4] = bflo(sv.z); a[5] = bfhi(sv.z); a[6] = bflo(sv.w); a[7] = bfhi(sv.w);
            }
        }
        int p = p0 + sub;
        for (; p + 2 < p1; p += 4) {
            int s0 = ecol[p], s1 = ecol[p + 2];
            uint4 u0 = hw4[(size_t)s0 * 8 + q];
            uint4 u1 = hw4[(size_t)s1 * 8 + q];
            a[0] += bflo(u0.x); a[1] += bfhi(u0.x); a[2] += bflo(u0.y); a[3] += bfhi(u0.y);
            a[4] += bflo(u0.z); a[5] += bfhi(u0.z); a[6] += bflo(u0.w); a[7] += bfhi(u0.w);
            a[0] += bflo(u1.x); a[1] += bfhi(u1.x); a[2] += bflo(u1.y); a[3] += bfhi(u1.y);
            a[4] += bflo(u1.z); a[5] += bfhi(u1.z); a[6] += bflo(u1.w); a[7] += bfhi(u1.w);
        }
        if (p < p1) {
            int s0 = ecol[p];
            uint4 u0 = hw4[(size_t)s0 * 8 + q];
            a[0] += bflo(u0.x); a[1] += bfhi(u0.x); a[2] += bflo(u0.y); a[3] += bfhi(u0.y);
            a[4] += bflo(u0.z); a[5] += bfhi(u0.z); a[6] += bflo(u0.w); a[7] += bfhi(u0.w);
        }
#pragma unroll
        for (int j = 0; j < 8; j++) a[j] += __shfl_xor(a[j], 8, 64);
        if (valid && sub == 0) {
            float di = dinv[row];
            float v[8];
#pragma unroll
            for (int j = 0; j < 8; j++) v[j] = a[j] * di;
            float4 o0 = make_float4(v[0], v[1], v[2], v[3]);
            float4 o1 = make_float4(v[4], v[5], v[6], v[7]);
            *(float4*)(agg + (size_t)row * 64 + 8 * q) = o0;
            *(float4*)(agg + (size_t)row * 64 + 8 * q + 4) = o1;
#pragma unroll
            for (int j = 0; j < 8; j++) {
                ls[j] += v[j];
                lq[j] = fmaf(v[j], v[j], lq[j]);
            }
        }
    }
#pragma unroll
    for (int j = 0; j < 8; j++) {
        ls[j] += __shfl_xor(ls[j], 16, 64); ls[j] += __shfl_xor(ls[j], 32, 64);
        lq[j] += __shfl_xor(lq[j], 16, 64); lq[j] += __shfl_xor(lq[j], 32, 64);
    }
    __shared__ float Ss[4][64], Sq[4][64];
    if (l < 8) {
#pragma unroll
        for (int j = 0; j < 8; j++) {
            Ss[w][8 * l + j] = ls[j];
            Sq[w][8 * l + j] = lq[j];
        }
    }
    __syncthreads();
    if (t < 64) {
        float a = Ss[0][t] + Ss[1][t] + Ss[2][t] + Ss[3][t];
        float b = Sq[0][t] + Sq[1][t] + Sq[2][t] + Sq[3][t];
        double* sh = sums + (blockIdx.x & 15) * 128;
        atomicAdd(&sh[t], (double)a);
        atomicAdd(&sh[64 + t], (double)b);
    }
}

// final-layer BN finalize (single launch after loop)
__global__ void k_finalize(const double* __restrict__ sums, const float* __restrict__ gamma,
                           const float* __restrict__ beta, float* __restrict__ ss) {
    int c = threadIdx.x;  // 64 threads
    double s = 0.0, q = 0.0;
#pragma unroll
    for (int k = 0; k < 16; k++) { s += sums[k * 128 + c]; q += sums[k * 128 + 64 + c]; }
    double mean = s / (double)NN;
    double var = q / (double)NN - mean * mean;
    float sc = gamma[c] * rsqrtf((float)var + BN_EPS);
    ss[c] = sc;
    ss[64 + c] = beta[c] - (float)mean * sc;
}

// final layer: xeb = bf16(xe + relu(agg*scale + shift))
__global__ void k_apply(const float* __restrict__ agg, const float* __restrict__ ss,
                        const float* __restrict__ xe, unsigned* __restrict__ xeb) {
    int i = blockIdx.x * blockDim.x + threadIdx.x;   // over NN*32 pairs
    if (i < NN * 32) {
        int i2 = i * 2;
        int c = i2 & 63;
        float2 av = *(const float2*)(agg + i2);
        float2 xv = *(const float2*)(xe + i2);
        float v0 = xv.x + fmaxf(fmaf(av.x, ss[c], ss[64 + c]), 0.f);
        float v1 = xv.y + fmaxf(fmaf(av.y, ss[c + 1], ss[64 + c + 1]), 0.f);
        xeb[i] = ((unsigned)f2bf(v1) << 16) | f2bf(v0);
    }
}

// out[e] = [xeb[s]; xeb[d]] @ fc_W + fc_b   (bf16 rows: 128B/row gather)
__global__ void k_out(const int* __restrict__ esrc, const int* __restrict__ edst,
                      const unsigned short* __restrict__ xeb, const float* __restrict__ fcW,
                      const float* __restrict__ fcb, float* __restrict__ out) {
    __shared__ float Ws[256];
    __shared__ float bs[2];
    int t = threadIdx.x;
    for (int i = t; i < 256; i += 256) Ws[i] = fcW[i];
    if (t < 2) bs[t] = fcb[t];
    __syncthreads();
    int e = blockIdx.x * blockDim.x + t;
    if (e < NEO) {
        int s = esrc[e], d = edst[e];
        const uint4* rs = (const uint4*)(xeb + (size_t)s * 64);
        const uint4* rd = (const uint4*)(xeb + (size_t)d * 64);
        float a0 = bs[0], a1 = bs[1];
#pragma unroll
        for (int i = 0; i < 8; i++) {
            uint4 v = rs[i];
            int c = i * 8;
            a0 += bflo(v.x) * Ws[(c + 0) * 2] + bfhi(v.x) * Ws[(c + 1) * 2] +
                  bflo(v.y) * Ws[(c + 2) * 2] + bfhi(v.y) * Ws[(c + 3) * 2] +
                  bflo(v.z) * Ws[(c + 4) * 2] + bfhi(v.z) * Ws[(c + 5) * 2] +
                  bflo(v.w) * Ws[(c + 6) * 2] + bfhi(v.w) * Ws[(c + 7) * 2];
            a1 += bflo(v.x) * Ws[(c + 0) * 2 + 1] + bfhi(v.x) * Ws[(c + 1) * 2 + 1] +
                  bflo(v.y) * Ws[(c + 2) * 2 + 1] + bfhi(v.y) * Ws[(c + 3) * 2 + 1] +
                  bflo(v.z) * Ws[(c + 4) * 2 + 1] + bfhi(v.z) * Ws[(c + 5) * 2 + 1] +
                  bflo(v.w) * Ws[(c + 6) * 2 + 1] + bfhi(v.w) * Ws[(c + 7) * 2 + 1];
        }
#pragma unroll
        for (int i = 0; i < 8; i++) {
            uint4 v = rd[i];
            int c = 64 + i * 8;
            a0 += bflo(v.x) * Ws[(c + 0) * 2] + bfhi(v.x) * Ws[(c + 1) * 2] +
                  bflo(v.y) * Ws[(c + 2) * 2] + bfhi(v.y) * Ws[(c + 3) * 2] +
                  bflo(v.z) * Ws[(c + 4) * 2] + bfhi(v.z) * Ws[(c + 5) * 2] +
                  bflo(v.w) * Ws[(c + 6) * 2] + bfhi(v.w) * Ws[(c + 7) * 2];
            a1 += bflo(v.x) * Ws[(c + 0) * 2 + 1] + bfhi(v.x) * Ws[(c + 1) * 2 + 1] +
                  bflo(v.y) * Ws[(c + 2) * 2 + 1] + bfhi(v.y) * Ws[(c + 3) * 2 + 1] +
                  bflo(v.z) * Ws[(c + 4) * 2 + 1] + bfhi(v.z) * Ws[(c + 5) * 2 + 1] +
                  bflo(v.w) * Ws[(c + 6) * 2 + 1] + bfhi(v.w) * Ws[(c + 7) * 2 + 1];
        }
        out[e * 2] = a0;
        out[e * 2 + 1] = a1;
    }
}

extern "C" void kernel_launch(void* const* d_in, const int* in_sizes, int n_in,
                              void* d_out, int out_size, void* d_ws, size_t ws_size,
                              hipStream_t stream) {
    const float* x      = (const float*)d_in[0];
    const int*   ei     = (const int*)d_in[1];
    const int*   eio    = (const int*)d_in[2];
    const float* W_emb  = (const float*)d_in[3];
    const float* b_emb  = (const float*)d_in[4];
    const float* conv_W = (const float*)d_in[5];
    // d_in[6] conv_b: cancels inside BN
    const float* bn_g   = (const float*)d_in[7];
    const float* bn_b   = (const float*)d_in[8];
    const float* fc_W   = (const float*)d_in[9];
    const float* fc_b   = (const float*)d_in[10];
    float* out = (float*)d_out;

    float* ws   = (float*)d_ws;
    int*   ecol = (int*)(ws + OFF_ECOL);
    float* xe   = ws + OFF_XE;
    float* agg  = ws + OFF_AGG;
    unsigned short* hwb = (unsigned short*)(ws + OFF_HWB);
    unsigned* xeb = (unsigned*)(ws + OFF_XEB);

    float* od     = (float*)d_out;
    float* dinv   = od + OD_DINV;
    int*   rowptr = (int*)(od + OD_ROWPTR);
    int*   cc     = (int*)(od + OD_CC);
    int*   bsum   = (int*)(od + OD_BSUM);
    float* ss     = od + OD_SS;
    double* sums  = (double*)(od + OD_SUMS);   // 2 x 2048 doubles, ping-pong

    const int* src  = ei;
    const int* dst  = ei + NE;
    const int* esrc = eio;
    const int* edst = eio + NEO;

    // ---- one-time CSR build (R10-proven path) ----
    (void)hipMemsetAsync(cc, 0, NN * sizeof(int), stream);
    k_hist<<<(NE + 255) / 256, 256, 0, stream>>>(dst, cc);
    k_scanA<<<SCAN_NB, SCAN_BS, 0, stream>>>(cc, rowptr, bsum, dinv);
    k_scanB<<<1, 256, 0, stream>>>(bsum);
    k_scanC<<<SCAN_NB, SCAN_BS, 0, stream>>>(rowptr, bsum, cc);
    k_build<<<8 * BUILD_BPG, 256, 0, stream>>>(src, dst, cc, ecol);

    k_embed<<<(NN + 63) / 64, 256, 0, stream>>>(x, W_emb, b_emb, xe);

    for (int l = 0; l < NL; l++) {
        double* sumsPrev = sums + ((l + 1) & 1) * 2048;
        double* sumsCur  = sums + (l & 1) * 2048;
        k_hw<<<(NN + 63) / 64, 256, 0, stream>>>(xe, xe, conv_W + l * 64 * 64, dinv, agg,
                                                 bn_g + (l ? (l - 1) * 64 : 0),
                                                 bn_b + (l ? (l - 1) * 64 : 0),
                                                 sumsPrev, sumsCur, hwb, l > 0 ? 1 : 0);
        k_spmm<<<SPMM_BLOCKS, 256, 0, stream>>>(rowptr, ecol, hwb, dinv, agg, sumsCur);
    }
    k_finalize<<<1, 64, 0, stream>>>(sums + ((NL - 1) & 1) * 2048,
                                     bn_g + (NL - 1) * 64, bn_b + (NL - 1) * 64, ss);
    k_apply<<<(NN * 32 + 255) / 256, 256, 0, stream>>>(agg, ss, xe, xeb);

    k_out<<<(NEO + 255) / 256, 256, 0, stream>>>(esrc, edst, (const unsigned short*)xeb,
                                                 fc_W, fc_b, out);
}

// Round 15
// 571.953 us; speedup vs baseline: 1.1109x; 1.0960x over previous
//
#include <hip/hip_runtime.h>

#define NN 100000
#define NE 1600000
#define NEO 400000
#define HID 64
#define NL 6
#define BN_EPS 1e-5f

#define SPMM_BLOCKS 6250
#define SCAN_BS 512
#define SCAN_NB 196   // ceil(100000/512)
#define GRP_ROWS 12500          // NN/8 rows per XCD group (build only)
#define BUILD_BPG 784           // blocks per group for build

// ---- d_ws layout (float offsets): 44.8MB ----
#define OFF_ECOL 0                        // NE ints
#define OFF_XE   NE                       // NN*64 bf16 = NN*32 f (residual)
#define OFF_AGG  (OFF_XE + NN * 32)       // NN*64 bf16
#define OFF_HWB  (OFF_AGG + NN * 32)      // NN*64 bf16

// ---- d_out head used as scratch (dead before k_out overwrites) ----
#define OD_DINV   0                      // NN f
#define OD_ROWPTR 100352                 // NN+1 ints
#define OD_CC     200704                 // NN ints (counts, then cursors)
#define OD_BSUM   300704                 // 256 ints
#define OD_SS     300960                 // 128 f (scale/shift, final layer)
#define OD_SUMS   301088                 // 2 x 2048 doubles (ping-pong), 8B-aligned

typedef __attribute__((ext_vector_type(8))) short bf16x8;
typedef __attribute__((ext_vector_type(4))) float f32x4;

static __device__ __forceinline__ unsigned short f2bf(float f) {
    unsigned u = __float_as_uint(f);
    unsigned r = (u + 0x7FFF + ((u >> 16) & 1)) >> 16;  // RNE
    return (unsigned short)r;
}
static __device__ __forceinline__ float bflo(unsigned u) {
    return __uint_as_float(u << 16);
}
static __device__ __forceinline__ float bfhi(unsigned u) {
    return __uint_as_float(u & 0xFFFF0000u);
}

// single-pass histogram (proven R10)
__global__ void k_hist(const int* __restrict__ dst, int* __restrict__ cnt) {
    int e = blockIdx.x * blockDim.x + threadIdx.x;
    if (e < NE) atomicAdd(&cnt[dst[e]], 1);
}

__global__ void k_scanA(const int* __restrict__ cnt, int* __restrict__ rowptr,
                        int* __restrict__ bsum, float* __restrict__ dinv) {
    __shared__ int sh[SCAN_BS];
    int t = threadIdx.x;
    int i = blockIdx.x * SCAN_BS + t;
    int v = (i < NN) ? cnt[i] : 0;
    sh[t] = v;
    __syncthreads();
    for (int off = 1; off < SCAN_BS; off <<= 1) {
        int a = (t >= off) ? sh[t - off] : 0;
        __syncthreads();
        sh[t] += a;
        __syncthreads();
    }
    if (i < NN) {
        rowptr[i] = sh[t] - v;
        dinv[i] = rsqrtf((float)(v + 1));   // deg = in-deg + self-loop
    }
    if (t == SCAN_BS - 1) bsum[blockIdx.x] = sh[t];
}

__global__ void k_scanB(int* __restrict__ bsum) {
    __shared__ int sh[256];
    int t = threadIdx.x;
    int v = (t < SCAN_NB) ? bsum[t] : 0;
    sh[t] = v;
    __syncthreads();
    for (int off = 1; off < 256; off <<= 1) {
        int a = (t >= off) ? sh[t - off] : 0;
        __syncthreads();
        sh[t] += a;
        __syncthreads();
    }
    if (t < SCAN_NB) bsum[t] = (t == 0) ? 0 : sh[t - 1];
}

__global__ void k_scanC(int* __restrict__ rowptr, const int* __restrict__ bsum,
                        int* __restrict__ cursor) {
    int i = blockIdx.x * SCAN_BS + threadIdx.x;
    if (i < NN) {
        int rp = rowptr[i] + bsum[blockIdx.x];
        rowptr[i] = rp;
        cursor[i] = rp;
    }
    if (i == 0) rowptr[NN] = NE;
}

// XCD-partitioned CSR scatter (proven R5..R14)
__global__ void k_build(const int* __restrict__ src, const int* __restrict__ dst,
                        int* __restrict__ cursor, int* __restrict__ ecol) {
    int g = blockIdx.x & 7;
    int b = blockIdx.x >> 3;
    int lo = g * GRP_ROWS, hi = lo + GRP_ROWS;
    for (int e = b * blockDim.x + threadIdx.x; e < NE; e += BUILD_BPG * blockDim.x) {
        int d = dst[e];
        if (d >= lo && d < hi) {
            int pos = atomicAdd(&cursor[d], 1);
            ecol[pos] = src[e];
        }
    }
}

// xe = bf16(x[NN,16] @ W[16,64] + b)
__global__ void k_embed(const float* __restrict__ x, const float* __restrict__ W,
                        const float* __restrict__ b, unsigned short* __restrict__ xe16) {
    __shared__ float Ws[16 * 64];
    __shared__ float bs[64];
    int t = threadIdx.x;
    for (int i = t; i < 16 * 64; i += 256) Ws[i] = W[i];
    if (t < 64) bs[t] = b[t];
    __syncthreads();
    int c = t & 63, r = t >> 6;
    int n0 = blockIdx.x * 64;
    for (int n = n0 + r; n < n0 + 64 && n < NN; n += 4) {
        const float* xr = x + n * 16;
        float acc = bs[c];
#pragma unroll
        for (int k = 0; k < 16; k++) acc = fmaf(xr[k], Ws[k * 64 + c], acc);
        xe16[(size_t)n * 64 + c] = f2bf(acc);
    }
}

// fused: BN-finalize (from sumsPrev) + xe(bf16) += relu(agg(bf16)*sc+sh)
//        + hwb = bf16(dinv*(xe@W))  [MFMA]
__global__ void k_hw(unsigned short* __restrict__ xe16,
                     const float* __restrict__ W, const float* __restrict__ dinv,
                     const unsigned short* __restrict__ agg16,
                     const float* __restrict__ gamma, const float* __restrict__ beta,
                     const double* __restrict__ sumsPrev, double* __restrict__ sumsCur,
                     unsigned short* __restrict__ hwb, int apply) {
    __shared__ unsigned short Wt[64 * 72];   // Wt[c][k], pitch 72
    __shared__ unsigned short Xb[64 * 72];   // Xb[n][k]
    __shared__ float sss[128];
    int t = threadIdx.x;
    int n0 = blockIdx.x * 64;
    if (blockIdx.x == 0) {
        for (int i = t; i < 2048; i += 256) sumsCur[i] = 0.0;
    }
    if (apply && t < 64) {   // in-block BN finalize
        double s = 0.0, q = 0.0;
#pragma unroll
        for (int k = 0; k < 16; k++) {
            s += sumsPrev[k * 128 + t];
            q += sumsPrev[k * 128 + 64 + t];
        }
        double mean = s / (double)NN;
        double var = q / (double)NN - mean * mean;
        float sc = gamma[t] * rsqrtf((float)var + BN_EPS);
        sss[t] = sc;
        sss[64 + t] = beta[t] - (float)mean * sc;
    }

    {   // stage Wt (transpose, bf16)
        int c = t & 63, r = t >> 6;
#pragma unroll
        for (int jj = 0; jj < 4; jj++) {
            float w0 = W[(r * 16 + jj * 4 + 0) * 64 + c];
            float w1 = W[(r * 16 + jj * 4 + 1) * 64 + c];
            float w2 = W[(r * 16 + jj * 4 + 2) * 64 + c];
            float w3 = W[(r * 16 + jj * 4 + 3) * 64 + c];
            uint2 pk;
            pk.x = ((unsigned)f2bf(w1) << 16) | f2bf(w0);
            pk.y = ((unsigned)f2bf(w3) << 16) | f2bf(w2);
            *(uint2*)&Wt[c * 72 + r * 16 + jj * 4] = pk;
        }
    }
    __syncthreads();   // Wt + sss ready

    {   // stage Xb (+apply fusion): thread (n=t>>2, kq=t&3) covers ch kq*16..+15
        int n = t >> 2, kq = t & 3;
        int node = n0 + n;
        unsigned xs[8] = {0, 0, 0, 0, 0, 0, 0, 0};
        if (node < NN) {
            const uint4* xr = (const uint4*)(xe16 + (size_t)node * 64 + kq * 16);
            uint4 x0 = xr[0], x1 = xr[1];
            xs[0] = x0.x; xs[1] = x0.y; xs[2] = x0.z; xs[3] = x0.w;
            xs[4] = x1.x; xs[5] = x1.y; xs[6] = x1.z; xs[7] = x1.w;
            if (apply) {
                const uint4* ar = (const uint4*)(agg16 + (size_t)node * 64 + kq * 16);
                uint4 a0 = ar[0], a1 = ar[1];
                unsigned as[8] = {a0.x, a0.y, a0.z, a0.w, a1.x, a1.y, a1.z, a1.w};
                int c = kq * 16;
#pragma unroll
                for (int i = 0; i < 8; i++) {
                    float v0 = bflo(xs[i]) +
                               fmaxf(fmaf(bflo(as[i]), sss[c + 2 * i], sss[64 + c + 2 * i]), 0.f);
                    float v1 = bfhi(xs[i]) +
                               fmaxf(fmaf(bfhi(as[i]), sss[c + 2 * i + 1], sss[64 + c + 2 * i + 1]), 0.f);
                    xs[i] = ((unsigned)f2bf(v1) << 16) | f2bf(v0);
                }
                uint4* xw = (uint4*)(xe16 + (size_t)node * 64 + kq * 16);
                xw[0] = make_uint4(xs[0], xs[1], xs[2], xs[3]);
                xw[1] = make_uint4(xs[4], xs[5], xs[6], xs[7]);
            }
        }
        *(uint4*)&Xb[n * 72 + kq * 16] = make_uint4(xs[0], xs[1], xs[2], xs[3]);
        *(uint4*)&Xb[n * 72 + kq * 16 + 8] = make_uint4(xs[4], xs[5], xs[6], xs[7]);
    }
    __syncthreads();

    int lane = t & 63, w = t >> 6;
    int m = lane & 15, quad = lane >> 4;
    f32x4 acc[4];
#pragma unroll
    for (int tc = 0; tc < 4; tc++) acc[tc] = (f32x4){0.f, 0.f, 0.f, 0.f};
#pragma unroll
    for (int s = 0; s < 2; s++) {
        bf16x8 bfr = *(const bf16x8*)&Xb[(w * 16 + m) * 72 + s * 32 + quad * 8];
#pragma unroll
        for (int tc = 0; tc < 4; tc++) {
            bf16x8 afr = *(const bf16x8*)&Wt[(tc * 16 + m) * 72 + s * 32 + quad * 8];
            acc[tc] = __builtin_amdgcn_mfma_f32_16x16x32_bf16(afr, bfr, acc[tc], 0, 0, 0);
        }
    }
    int node = n0 + w * 16 + m;
    if (node < NN) {
        float di = dinv[node];
#pragma unroll
        for (int tc = 0; tc < 4; tc++) {
            int c0 = tc * 16 + quad * 4;
            uint2 pk;
            pk.x = ((unsigned)f2bf(acc[tc][1] * di) << 16) | f2bf(acc[tc][0] * di);
            pk.y = ((unsigned)f2bf(acc[tc][3] * di) << 16) | f2bf(acc[tc][2] * di);
            *(uint2*)(hwb + (size_t)node * 64 + c0) = pk;
        }
    }
}

// agg16[d] = bf16(dinv[d]*(hwb[d] + sum_{s in N(d)} hwb[s])); BN stats on ROUNDED values.
// Wave = 4 rows x 16 lanes (2 sub-groups of 8); lane q holds ch 8q..8q+7 (uint4).
__global__ void k_spmm(const int* __restrict__ rowptr, const int* __restrict__ ecol,
                       const unsigned short* __restrict__ hwb, const float* __restrict__ dinv,
                       unsigned short* __restrict__ agg16, double* __restrict__ sums) {
    int t = threadIdx.x;
    int w = t >> 6, l = t & 63;
    int r = l >> 4;          // row slot 0..3
    int sub = (l >> 3) & 1;  // edge sub-group
    int q = l & 7;           // channel quad
    const uint4* hw4 = (const uint4*)hwb;
    float ls[8], lq[8];
#pragma unroll
    for (int j = 0; j < 8; j++) { ls[j] = 0.f; lq[j] = 0.f; }
    for (int row0 = blockIdx.x * 16 + w * 4; row0 < NN; row0 += SPMM_BLOCKS * 16) {
        int row = row0 + r;
        bool valid = row < NN;
        int p0 = 0, p1 = 0;
        float a[8];
#pragma unroll
        for (int j = 0; j < 8; j++) a[j] = 0.f;
        if (valid) {
            p0 = rowptr[row];
            p1 = rowptr[row + 1];
            if (sub == 0) {
                uint4 sv = hw4[(size_t)row * 8 + q];
                a[0] = bflo(sv.x); a[1] = bfhi(sv.x); a[2] = bflo(sv.y); a[3] = bfhi(sv.y);
                a[4] = bflo(sv.z); a[5] = bfhi(sv.z); a[6] = bflo(sv.w); a[7] = bfhi(sv.w);
            }
        }
        int p = p0 + sub;
        for (; p + 2 < p1; p += 4) {
            int s0 = ecol[p], s1 = ecol[p + 2];
            uint4 u0 = hw4[(size_t)s0 * 8 + q];
            uint4 u1 = hw4[(size_t)s1 * 8 + q];
            a[0] += bflo(u0.x); a[1] += bfhi(u0.x); a[2] += bflo(u0.y); a[3] += bfhi(u0.y);
            a[4] += bflo(u0.z); a[5] += bfhi(u0.z); a[6] += bflo(u0.w); a[7] += bfhi(u0.w);
            a[0] += bflo(u1.x); a[1] += bfhi(u1.x); a[2] += bflo(u1.y); a[3] += bfhi(u1.y);
            a[4] += bflo(u1.z); a[5] += bfhi(u1.z); a[6] += bflo(u1.w); a[7] += bfhi(u1.w);
        }
        if (p < p1) {
            int s0 = ecol[p];
            uint4 u0 = hw4[(size_t)s0 * 8 + q];
            a[0] += bflo(u0.x); a[1] += bfhi(u0.x); a[2] += bflo(u0.y); a[3] += bfhi(u0.y);
            a[4] += bflo(u0.z); a[5] += bfhi(u0.z); a[6] += bflo(u0.w); a[7] += bfhi(u0.w);
        }
#pragma unroll
        for (int j = 0; j < 8; j++) a[j] += __shfl_xor(a[j], 8, 64);
        if (valid && sub == 0) {
            float di = dinv[row];
            unsigned pk[4];
#pragma unroll
            for (int j = 0; j < 4; j++) {
                float v0 = a[2 * j] * di, v1 = a[2 * j + 1] * di;
                pk[j] = ((unsigned)f2bf(v1) << 16) | f2bf(v0);
            }
            *(uint4*)(agg16 + (size_t)row * 64 + 8 * q) = make_uint4(pk[0], pk[1], pk[2], pk[3]);
            // stats on the rounded (stored) values -> BN self-consistent
#pragma unroll
            for (int j = 0; j < 4; j++) {
                float v0 = bflo(pk[j]), v1 = bfhi(pk[j]);
                ls[2 * j] += v0; ls[2 * j + 1] += v1;
                lq[2 * j] = fmaf(v0, v0, lq[2 * j]);
                lq[2 * j + 1] = fmaf(v1, v1, lq[2 * j + 1]);
            }
        }
    }
#pragma unroll
    for (int j = 0; j < 8; j++) {
        ls[j] += __shfl_xor(ls[j], 16, 64); ls[j] += __shfl_xor(ls[j], 32, 64);
        lq[j] += __shfl_xor(lq[j], 16, 64); lq[j] += __shfl_xor(lq[j], 32, 64);
    }
    __shared__ float Ss[4][64], Sq[4][64];
    if (l < 8) {
#pragma unroll
        for (int j = 0; j < 8; j++) {
            Ss[w][8 * l + j] = ls[j];
            Sq[w][8 * l + j] = lq[j];
        }
    }
    __syncthreads();
    if (t < 64) {
        float a = Ss[0][t] + Ss[1][t] + Ss[2][t] + Ss[3][t];
        float b = Sq[0][t] + Sq[1][t] + Sq[2][t] + Sq[3][t];
        double* sh = sums + (blockIdx.x & 15) * 128;
        atomicAdd(&sh[t], (double)a);
        atomicAdd(&sh[64 + t], (double)b);
    }
}

// final-layer BN finalize (single launch after loop)
__global__ void k_finalize(const double* __restrict__ sums, const float* __restrict__ gamma,
                           const float* __restrict__ beta, float* __restrict__ ss) {
    int c = threadIdx.x;  // 64 threads
    double s = 0.0, q = 0.0;
#pragma unroll
    for (int k = 0; k < 16; k++) { s += sums[k * 128 + c]; q += sums[k * 128 + 64 + c]; }
    double mean = s / (double)NN;
    double var = q / (double)NN - mean * mean;
    float sc = gamma[c] * rsqrtf((float)var + BN_EPS);
    ss[c] = sc;
    ss[64 + c] = beta[c] - (float)mean * sc;
}

// final layer: xe16 += relu(agg16*scale + shift)  (in-place bf16 update)
__global__ void k_apply(const unsigned short* __restrict__ agg16, const float* __restrict__ ss,
                        unsigned short* __restrict__ xe16) {
    int i = blockIdx.x * blockDim.x + threadIdx.x;   // uint4 index, NN*8 total
    if (i < NN * 8) {
        int c0 = (i & 7) * 8;
        uint4 av = *(const uint4*)(agg16 + (size_t)i * 8);
        uint4 xv = *(const uint4*)(xe16 + (size_t)i * 8);
        unsigned as[4] = {av.x, av.y, av.z, av.w};
        unsigned xs[4] = {xv.x, xv.y, xv.z, xv.w};
#pragma unroll
        for (int j = 0; j < 4; j++) {
            int c = c0 + 2 * j;
            float v0 = bflo(xs[j]) + fmaxf(fmaf(bflo(as[j]), ss[c], ss[64 + c]), 0.f);
            float v1 = bfhi(xs[j]) + fmaxf(fmaf(bfhi(as[j]), ss[c + 1], ss[64 + c + 1]), 0.f);
            xs[j] = ((unsigned)f2bf(v1) << 16) | f2bf(v0);
        }
        *(uint4*)(xe16 + (size_t)i * 8) = make_uint4(xs[0], xs[1], xs[2], xs[3]);
    }
}

// out[e] = [xe16[s]; xe16[d]] @ fc_W + fc_b   (bf16 rows: 128B/row gather)
__global__ void k_out(const int* __restrict__ esrc, const int* __restrict__ edst,
                      const unsigned short* __restrict__ xe16, const float* __restrict__ fcW,
                      const float* __restrict__ fcb, float* __restrict__ out) {
    __shared__ float Ws[256];
    __shared__ float bs[2];
    int t = threadIdx.x;
    for (int i = t; i < 256; i += 256) Ws[i] = fcW[i];
    if (t < 2) bs[t] = fcb[t];
    __syncthreads();
    int e = blockIdx.x * blockDim.x + t;
    if (e < NEO) {
        int s = esrc[e], d = edst[e];
        const uint4* rs = (const uint4*)(xe16 + (size_t)s * 64);
        const uint4* rd = (const uint4*)(xe16 + (size_t)d * 64);
        float a0 = bs[0], a1 = bs[1];
#pragma unroll
        for (int i = 0; i < 8; i++) {
            uint4 v = rs[i];
            int c = i * 8;
            a0 += bflo(v.x) * Ws[(c + 0) * 2] + bfhi(v.x) * Ws[(c + 1) * 2] +
                  bflo(v.y) * Ws[(c + 2) * 2] + bfhi(v.y) * Ws[(c + 3) * 2] +
                  bflo(v.z) * Ws[(c + 4) * 2] + bfhi(v.z) * Ws[(c + 5) * 2] +
                  bflo(v.w) * Ws[(c + 6) * 2] + bfhi(v.w) * Ws[(c + 7) * 2];
            a1 += bflo(v.x) * Ws[(c + 0) * 2 + 1] + bfhi(v.x) * Ws[(c + 1) * 2 + 1] +
                  bflo(v.y) * Ws[(c + 2) * 2 + 1] + bfhi(v.y) * Ws[(c + 3) * 2 + 1] +
                  bflo(v.z) * Ws[(c + 4) * 2 + 1] + bfhi(v.z) * Ws[(c + 5) * 2 + 1] +
                  bflo(v.w) * Ws[(c + 6) * 2 + 1] + bfhi(v.w) * Ws[(c + 7) * 2 + 1];
        }
#pragma unroll
        for (int i = 0; i < 8; i++) {
            uint4 v = rd[i];
            int c = 64 + i * 8;
            a0 += bflo(v.x) * Ws[(c + 0) * 2] + bfhi(v.x) * Ws[(c + 1) * 2] +
                  bflo(v.y) * Ws[(c + 2) * 2] + bfhi(v.y) * Ws[(c + 3) * 2] +
                  bflo(v.z) * Ws[(c + 4) * 2] + bfhi(v.z) * Ws[(c + 5) * 2] +
                  bflo(v.w) * Ws[(c + 6) * 2] + bfhi(v.w) * Ws[(c + 7) * 2];
            a1 += bflo(v.x) * Ws[(c + 0) * 2 + 1] + bfhi(v.x) * Ws[(c + 1) * 2 + 1] +
                  bflo(v.y) * Ws[(c + 2) * 2 + 1] + bfhi(v.y) * Ws[(c + 3) * 2 + 1] +
                  bflo(v.z) * Ws[(c + 4) * 2 + 1] + bfhi(v.z) * Ws[(c + 5) * 2 + 1] +
                  bflo(v.w) * Ws[(c + 6) * 2 + 1] + bfhi(v.w) * Ws[(c + 7) * 2 + 1];
        }
        out[e * 2] = a0;
        out[e * 2 + 1] = a1;
    }
}

extern "C" void kernel_launch(void* const* d_in, const int* in_sizes, int n_in,
                              void* d_out, int out_size, void* d_ws, size_t ws_size,
                              hipStream_t stream) {
    const float* x      = (const float*)d_in[0];
    const int*   ei     = (const int*)d_in[1];
    const int*   eio    = (const int*)d_in[2];
    const float* W_emb  = (const float*)d_in[3];
    const float* b_emb  = (const float*)d_in[4];
    const float* conv_W = (const float*)d_in[5];
    // d_in[6] conv_b: cancels inside BN
    const float* bn_g   = (const float*)d_in[7];
    const float* bn_b   = (const float*)d_in[8];
    const float* fc_W   = (const float*)d_in[9];
    const float* fc_b   = (const float*)d_in[10];
    float* out = (float*)d_out;

    float* ws   = (float*)d_ws;
    int*   ecol = (int*)(ws + OFF_ECOL);
    unsigned short* xe16  = (unsigned short*)(ws + OFF_XE);
    unsigned short* agg16 = (unsigned short*)(ws + OFF_AGG);
    unsigned short* hwb   = (unsigned short*)(ws + OFF_HWB);

    float* od     = (float*)d_out;
    float* dinv   = od + OD_DINV;
    int*   rowptr = (int*)(od + OD_ROWPTR);
    int*   cc     = (int*)(od + OD_CC);
    int*   bsum   = (int*)(od + OD_BSUM);
    float* ss     = od + OD_SS;
    double* sums  = (double*)(od + OD_SUMS);   // 2 x 2048 doubles, ping-pong

    const int* src  = ei;
    const int* dst  = ei + NE;
    const int* esrc = eio;
    const int* edst = eio + NEO;

    // ---- one-time CSR build (R10-proven path) ----
    (void)hipMemsetAsync(cc, 0, NN * sizeof(int), stream);
    k_hist<<<(NE + 255) / 256, 256, 0, stream>>>(dst, cc);
    k_scanA<<<SCAN_NB, SCAN_BS, 0, stream>>>(cc, rowptr, bsum, dinv);
    k_scanB<<<1, 256, 0, stream>>>(bsum);
    k_scanC<<<SCAN_NB, SCAN_BS, 0, stream>>>(rowptr, bsum, cc);
    k_build<<<8 * BUILD_BPG, 256, 0, stream>>>(src, dst, cc, ecol);

    k_embed<<<(NN + 63) / 64, 256, 0, stream>>>(x, W_emb, b_emb, xe16);

    for (int l = 0; l < NL; l++) {
        double* sumsPrev = sums + ((l + 1) & 1) * 2048;
        double* sumsCur  = sums + (l & 1) * 2048;
        k_hw<<<(NN + 63) / 64, 256, 0, stream>>>(xe16, conv_W + l * 64 * 64, dinv, agg16,
                                                 bn_g + (l ? (l - 1) * 64 : 0),
                                                 bn_b + (l ? (l - 1) * 64 : 0),
                                                 sumsPrev, sumsCur, hwb, l > 0 ? 1 : 0);
        k_spmm<<<SPMM_BLOCKS, 256, 0, stream>>>(rowptr, ecol, hwb, dinv, agg16, sumsCur);
    }
    k_finalize<<<1, 64, 0, stream>>>(sums + ((NL - 1) & 1) * 2048,
                                     bn_g + (NL - 1) * 64, bn_b + (NL - 1) * 64, ss);
    k_apply<<<(NN * 8 + 255) / 256, 256, 0, stream>>>(agg16, ss, xe16);

    k_out<<<(NEO + 255) / 256, 256, 0, stream>>>(esrc, edst, xe16, fc_W, fc_b, out);
}